// Round 14
// baseline (547.046 us; speedup 1.0000x reference)
//
#include <hip/hip_runtime.h>
#include <math.h>

#define NUM_USERS 100000
#define NUM_ITEMS 50000
#define EMBED     64
#define NUM_EDGES 3276800
#define BATCH     16384
#define CAP       13824       // fits input (~11580+5s) AND 32-padded output (~12450+12s)
#define NBUCK     391
#define P1_EDGES  8192
#define P1_THREADS 512
#define P2_THREADS 1024
#define CVT_BLOCKS 1563       // ceil(50000*64/8 / 256)

typedef _Float16 half8 __attribute__((ext_vector_type(8)));

// ---------- prep: fused cvt + workspace zeroing ----------
__global__ void prep_kernel(const float* __restrict__ itab, _Float16* __restrict__ it16,
                            int* __restrict__ curzero, _Float16* __restrict__ w16) {
    int b = blockIdx.x;
    if (b < CVT_BLOCKS) {
        int i = b * 256 + threadIdx.x;
        if (i < NUM_ITEMS * EMBED / 8) {
            const float4* p = (const float4*)itab + 2 * i;
            float4 a = p[0], c = p[1];
            half8 o;
            o[0] = (_Float16)a.x; o[1] = (_Float16)a.y; o[2] = (_Float16)a.z; o[3] = (_Float16)a.w;
            o[4] = (_Float16)c.x; o[5] = (_Float16)c.y; o[6] = (_Float16)c.z; o[7] = (_Float16)c.w;
            ((half8*)it16)[i] = o;
        }
    } else if (b == CVT_BLOCKS) {
        for (int k = threadIdx.x; k < 800; k += 256) curzero[k] = 0;
    } else {
        int i = threadIdx.x;
        if (i < 64) w16[(long long)NUM_USERS * EMBED + i] = (_Float16)0.f;
        else if (i < 128) it16[(long long)NUM_ITEMS * EMBED + (i - 64)] = (_Float16)0.f;
    }
}

// ---------- pass 1: register-stashed edges, LDS-staged line-aligned bucket scatter ----------
__global__ void __launch_bounds__(P1_THREADS)
pass1_kernel(const int* __restrict__ rows, const int* __restrict__ cols,
             int* __restrict__ ucur, int* __restrict__ icur,
             int* __restrict__ rec_u, int* __restrict__ rec_i) {
    __shared__ int hu[400], hi[400], gu[400], gi[400];
    __shared__ int lbase[400], lcur[400];
    __shared__ int sc[512];
    __shared__ int recbuf[P1_EDGES];
    int t = threadIdx.x;
    long long e0 = (long long)blockIdx.x * P1_EDGES;

    int er[16], ec[16];
    #pragma unroll
    for (int q = 0; q < 16; ++q) {
        er[q] = rows[e0 + t + q * P1_THREADS];
        ec[q] = cols[e0 + t + q * P1_THREADS];
    }

    for (int i = t; i < 400; i += P1_THREADS) { hu[i] = 0; hi[i] = 0; }
    __syncthreads();
    #pragma unroll
    for (int q = 0; q < 16; ++q) {
        atomicAdd(&hu[er[q] >> 8], 1);
        atomicAdd(&hi[ec[q] >> 7], 1);
    }
    __syncthreads();
    for (int i = t; i < 400; i += P1_THREADS) {
        int vr = (hu[i] + 15) & ~15;
        gu[i] = vr ? atomicAdd(&ucur[i], vr) : 0;
        vr = (hi[i] + 15) & ~15;
        gi[i] = vr ? atomicAdd(&icur[i], vr) : 0;
    }

    // ===== user phase =====
    __syncthreads();
    sc[t] = (t < 400) ? hu[t] : 0;
    __syncthreads();
    for (int o = 1; o < 512; o <<= 1) {
        int x = (t >= o) ? sc[t - o] : 0; __syncthreads();
        sc[t] += x; __syncthreads();
    }
    if (t < 400) { lbase[t] = sc[t] - hu[t]; lcur[t] = 0; }
    __syncthreads();
    #pragma unroll
    for (int q = 0; q < 16; ++q) {
        int b = er[q] >> 8;
        int p = lbase[b] + atomicAdd(&lcur[b], 1);
        recbuf[p] = (ec[q] << 8) | (er[q] & 255);
    }
    __syncthreads();
    sc[t] = (t < 400) ? ((hu[t] + 15) & ~15) : 0;
    __syncthreads();
    for (int o = 1; o < 512; o <<= 1) {
        int x = (t >= o) ? sc[t - o] : 0; __syncthreads();
        sc[t] += x; __syncthreads();
    }
    int total = sc[511];
    for (int o4 = t * 4; o4 < total; o4 += P1_THREADS * 4) {
        int lo = 0, hi_ = 399;
        while (lo < hi_) { int mid = (lo + hi_) >> 1; if (sc[mid] > o4) hi_ = mid; else lo = mid + 1; }
        int b = lo;
        int v = hu[b];
        int vr = (v + 15) & ~15;
        int j = o4 - (sc[b] - vr);
        int gpos = gu[b] + j;
        if (gpos + 3 < CAP) {
            int4 val;
            val.x = (j + 0 < v) ? recbuf[lbase[b] + j + 0] : -1;
            val.y = (j + 1 < v) ? recbuf[lbase[b] + j + 1] : -1;
            val.z = (j + 2 < v) ? recbuf[lbase[b] + j + 2] : -1;
            val.w = (j + 3 < v) ? recbuf[lbase[b] + j + 3] : -1;
            *(int4*)(rec_u + (long long)b * CAP + gpos) = val;
        } else {
            for (int k = 0; k < 4; ++k)
                if (gpos + k < CAP)
                    rec_u[(long long)b * CAP + gpos + k] = (j + k < v) ? recbuf[lbase[b] + j + k] : -1;
        }
    }

    // ===== item phase =====
    __syncthreads();
    sc[t] = (t < 400) ? hi[t] : 0;
    __syncthreads();
    for (int o = 1; o < 512; o <<= 1) {
        int x = (t >= o) ? sc[t - o] : 0; __syncthreads();
        sc[t] += x; __syncthreads();
    }
    if (t < 400) { lbase[t] = sc[t] - hi[t]; lcur[t] = 0; }
    __syncthreads();
    #pragma unroll
    for (int q = 0; q < 16; ++q) {
        int b = ec[q] >> 7;
        int p = lbase[b] + atomicAdd(&lcur[b], 1);
        recbuf[p] = (er[q] << 7) | (ec[q] & 127);
    }
    __syncthreads();
    sc[t] = (t < 400) ? ((hi[t] + 15) & ~15) : 0;
    __syncthreads();
    for (int o = 1; o < 512; o <<= 1) {
        int x = (t >= o) ? sc[t - o] : 0; __syncthreads();
        sc[t] += x; __syncthreads();
    }
    total = sc[511];
    for (int o4 = t * 4; o4 < total; o4 += P1_THREADS * 4) {
        int lo = 0, hi_ = 399;
        while (lo < hi_) { int mid = (lo + hi_) >> 1; if (sc[mid] > o4) hi_ = mid; else lo = mid + 1; }
        int b = lo;
        int v = hi[b];
        int vr = (v + 15) & ~15;
        int j = o4 - (sc[b] - vr);
        int gpos = gi[b] + j;
        if (gpos + 3 < CAP) {
            int4 val;
            val.x = (j + 0 < v) ? recbuf[lbase[b] + j + 0] : -1;
            val.y = (j + 1 < v) ? recbuf[lbase[b] + j + 1] : -1;
            val.z = (j + 2 < v) ? recbuf[lbase[b] + j + 2] : -1;
            val.w = (j + 3 < v) ? recbuf[lbase[b] + j + 3] : -1;
            *(int4*)(rec_i + (long long)b * CAP + gpos) = val;
        } else {
            for (int k = 0; k < 4; ++k)
                if (gpos + k < CAP)
                    rec_i[(long long)b * CAP + gpos + k] = (j + k < v) ? recbuf[lbase[b] + j + k] : -1;
        }
    }
}

// ---------- pass 2: per-bucket fine sort; runs padded to x32 with zero-row sentinel ----------
template <int VBITS>
__device__ __forceinline__ void pass2_body(int* __restrict__ rec, const int* __restrict__ cur,
                                           int* __restrict__ rdeg, int* __restrict__ pdeg,
                                           int* __restrict__ off, float* __restrict__ inv32,
                                           int ncap, int sentinel, int b,
                                           int* buf, int* h, int* ex, int* cnt, int* sc) {
    const int V = 1 << VBITS, M = V - 1;
    int t = threadIdx.x;
    long long s = (long long)b * CAP;
    int n = cur[b]; if (n > CAP) n = CAP;
    int nv = (n + 3) >> 2;
    const int4* rec4 = (const int4*)(rec + s);
    for (int i = t; i < nv; i += P2_THREADS) {
        int4 v4 = rec4[i];
        buf[4 * i + 0] = v4.x; buf[4 * i + 1] = v4.y;
        buf[4 * i + 2] = v4.z; buf[4 * i + 3] = v4.w;
    }
    if (t < V) { h[t] = 0; cnt[t] = 0; }
    __syncthreads();
    for (int i = t; i < n; i += P2_THREADS) {
        int r = buf[i];
        if (r != -1) atomicAdd(&h[r & M], 1);
    }
    __syncthreads();
    if (t < V) sc[t] = (h[t] + 31) & ~31;         // padded run length
    __syncthreads();
    for (int o = 1; o < V; o <<= 1) {
        int x = (t >= o && t < V) ? sc[t - o] : 0;
        __syncthreads();
        if (t < V) sc[t] += x;
        __syncthreads();
    }
    if (t < V) {
        int hpv = (h[t] + 31) & ~31;
        ex[t] = sc[t] - hpv;                      // exclusive padded offset
        int id = b * V + t;
        if (id < ncap) {
            int v = h[t];
            rdeg[id] = v;
            pdeg[id] = hpv;
            off[id] = (int)(s + ex[t]);
            if (inv32) inv32[id] = v ? 1.0f / (float)v : 0.0f;
        }
    }
    __syncthreads();
    for (int i = t; i < n; i += P2_THREADS) {
        int r = buf[i];
        if (r == -1) continue;
        int k = r & M;
        int rnk = atomicAdd(&cnt[k], 1);
        rec[s + ex[k] + rnk] = (int)(((unsigned)r) >> VBITS);
    }
    __syncthreads();
    if (t < V) {                                  // sentinel-fill the per-run pad
        int basep = (int)(s + ex[t]);
        int v = h[t];
        int hpv = (v + 31) & ~31;
        for (int j = v; j < hpv; ++j) rec[basep + j] = sentinel;
    }
}

__global__ void __launch_bounds__(P2_THREADS)
pass2_kernel(int* __restrict__ rec_u, const int* __restrict__ ucur,
             int* __restrict__ udeg, int* __restrict__ updeg,
             int* __restrict__ uoff, float* __restrict__ inv32,
             int* __restrict__ rec_i, const int* __restrict__ icur,
             int* __restrict__ ideg, int* __restrict__ ipdeg, int* __restrict__ ioff) {
    __shared__ int buf[CAP];
    __shared__ int h[256], ex[256], cnt[256], sc[256];
    if (blockIdx.x < NBUCK)
        pass2_body<8>(rec_u, ucur, udeg, updeg, uoff, inv32, NUM_USERS, NUM_ITEMS,
                      blockIdx.x, buf, h, ex, cnt, sc);
    else
        pass2_body<7>(rec_i, icur, ideg, ipdeg, ioff, (float*)nullptr, NUM_ITEMS, NUM_USERS,
                      blockIdx.x - NBUCK, buf, h, ex, cnt, sc);
}

// ---------- gather_u: sentinel-padded runs -> zero-check inner loop ----------
__global__ void gather_u(const int* __restrict__ uoff, const int* __restrict__ updeg,
                         const int* __restrict__ csr_col, const float* __restrict__ inv32,
                         const _Float16* __restrict__ it, _Float16* __restrict__ w) {
    int row = blockIdx.x * 4 + (threadIdx.x >> 6);
    if (row >= NUM_USERS) return;
    int lane = threadIdx.x & 63;
    int slot = lane >> 3;
    int h    = lane & 7;
    int start = uoff[row];
    int pend = start + updeg[row];
    half8 acc = {0, 0, 0, 0, 0, 0, 0, 0};
    for (int k = start; k < pend; k += 32) {
        int c0 = csr_col[k + slot];
        int c1 = csr_col[k + slot + 8];
        int c2 = csr_col[k + slot + 16];
        int c3 = csr_col[k + slot + 24];
        half8 x0 = *(const half8*)(it + (long long)c0 * EMBED + (h << 3));
        half8 x1 = *(const half8*)(it + (long long)c1 * EMBED + (h << 3));
        half8 x2 = *(const half8*)(it + (long long)c2 * EMBED + (h << 3));
        half8 x3 = *(const half8*)(it + (long long)c3 * EMBED + (h << 3));
        acc += x0; acc += x1; acc += x2; acc += x3;
    }
    float f[8];
    #pragma unroll
    for (int j = 0; j < 8; ++j) {
        f[j] = (float)acc[j];
        f[j] += __shfl_xor(f[j], 8, 64);
        f[j] += __shfl_xor(f[j], 16, 64);
        f[j] += __shfl_xor(f[j], 32, 64);
    }
    if (lane < 8) {
        float v = inv32[row];
        float v2 = v * v;
        half8 ow;
        #pragma unroll
        for (int j = 0; j < 8; ++j) ow[j] = (_Float16)(f[j] * v2);
        *(half8*)(w + (long long)row * EMBED + (lane << 3)) = ow;
    }
}

// ---------- gather_it: sentinel-padded runs ----------
__global__ void gather_it(const int* __restrict__ ioff, const int* __restrict__ ipdeg,
                          const int* __restrict__ csc_row,
                          const _Float16* __restrict__ w, _Float16* __restrict__ it) {
    int col = blockIdx.x * 4 + (threadIdx.x >> 6);
    if (col >= NUM_ITEMS) return;
    int lane = threadIdx.x & 63;
    int slot = lane >> 3;
    int h    = lane & 7;
    int start = ioff[col];
    int pend = start + ipdeg[col];
    half8 acc = {0, 0, 0, 0, 0, 0, 0, 0};
    for (int k = start; k < pend; k += 32) {
        int r0 = csc_row[k + slot];
        int r1 = csc_row[k + slot + 8];
        int r2 = csc_row[k + slot + 16];
        int r3 = csc_row[k + slot + 24];
        half8 x0 = *(const half8*)(w + (long long)r0 * EMBED + (h << 3));
        half8 x1 = *(const half8*)(w + (long long)r1 * EMBED + (h << 3));
        half8 x2 = *(const half8*)(w + (long long)r2 * EMBED + (h << 3));
        half8 x3 = *(const half8*)(w + (long long)r3 * EMBED + (h << 3));
        acc += x0; acc += x1; acc += x2; acc += x3;
    }
    float f[8];
    #pragma unroll
    for (int j = 0; j < 8; ++j) {
        f[j] = (float)acc[j];
        f[j] += __shfl_xor(f[j], 8, 64);
        f[j] += __shfl_xor(f[j], 16, 64);
        f[j] += __shfl_xor(f[j], 32, 64);
    }
    if (lane < 8) {
        half8 o;
        #pragma unroll
        for (int j = 0; j < 8; ++j) o[j] = (_Float16)f[j];
        *(half8*)(it + (long long)col * EMBED + (lane << 3)) = o;
    }
}

// ---------- fused last layer: it3 row in registers -> dot with deg*w3 -> sigmoid ----------
__global__ void batch_score(const int* __restrict__ ioff, const int* __restrict__ ipdeg,
                            const int* __restrict__ csc_row, const _Float16* __restrict__ w,
                            const int* __restrict__ udeg,
                            const int* __restrict__ uidx, const int* __restrict__ iidx,
                            float* __restrict__ out) {
    int b = blockIdx.x * 4 + (threadIdx.x >> 6);
    if (b >= BATCH) return;
    int lane = threadIdx.x & 63;
    int col = iidx[b];
    int slot = lane >> 3;
    int h    = lane & 7;
    int start = ioff[col];
    int pend = start + ipdeg[col];
    half8 acc = {0, 0, 0, 0, 0, 0, 0, 0};
    for (int k = start; k < pend; k += 32) {
        int r0 = csc_row[k + slot];
        int r1 = csc_row[k + slot + 8];
        int r2 = csc_row[k + slot + 16];
        int r3 = csc_row[k + slot + 24];
        half8 x0 = *(const half8*)(w + (long long)r0 * EMBED + (h << 3));
        half8 x1 = *(const half8*)(w + (long long)r1 * EMBED + (h << 3));
        half8 x2 = *(const half8*)(w + (long long)r2 * EMBED + (h << 3));
        half8 x3 = *(const half8*)(w + (long long)r3 * EMBED + (h << 3));
        acc += x0; acc += x1; acc += x2; acc += x3;
    }
    float f[8];
    #pragma unroll
    for (int j = 0; j < 8; ++j) {
        f[j] = (float)acc[j];
        f[j] += __shfl_xor(f[j], 8, 64);
        f[j] += __shfl_xor(f[j], 16, 64);
        f[j] += __shfl_xor(f[j], 32, 64);
    }
    int ui = uidx[b];
    half8 wv = *(const half8*)(w + (long long)ui * EMBED + (h << 3));
    float p = 0.f;
    #pragma unroll
    for (int j = 0; j < 8; ++j) p += f[j] * (float)wv[j];
    p += __shfl_xor(p, 1, 64);
    p += __shfl_xor(p, 2, 64);
    p += __shfl_xor(p, 4, 64);
    if (lane == 0) {
        float s = p * (float)udeg[ui];   // u3 = deg * w3
        out[b] = 1.0f / (1.0f + expf(-s));
    }
}

extern "C" void kernel_launch(void* const* d_in, const int* in_sizes, int n_in,
                              void* d_out, int out_size, void* d_ws, size_t ws_size,
                              hipStream_t stream) {
    const float* item_table = (const float*)d_in[1];
    const int*   rows       = (const int*)d_in[2];
    const int*   cols       = (const int*)d_in[3];
    const int*   uidx       = (const int*)d_in[4];
    const int*   iidx       = (const int*)d_in[5];
    float* out = (float*)d_out;

    // workspace layout (byte offsets)
    char* base = (char*)d_ws;
    int*   udeg  = (int*)(base + 0);                    // 100000 i (real deg)
    int*   ideg  = (int*)(base +   400000);             // 50000 i (real deg, unused downstream)
    int*   uoff  = (int*)(base +   600000);             // 100000 i
    int*   ioff  = (int*)(base +  1000000);             // 50000 i
    float* inv32 = (float*)(base + 1200000);            // 100000 f
    int*   updeg = (int*)(base +  1600000);             // 100000 i (padded deg)
    int*   ipdeg = (int*)(base +  2000000);             // 50000 i (padded deg)
    int*   ucur  = (int*)(base +  2200000);             // 400 i
    int*   icur  = (int*)(base +  2201600);             // 400 i (contiguous with ucur)
    int*   rec_u = (int*)(base +  2203200);             // 400*CAP i = 22.1 MB
    int*   rec_i = (int*)(base + 24321600);             // 400*CAP i = 22.1 MB
    _Float16* w16  = (_Float16*)(base + 46440000);      // (100000+1)*64 h = 12.8 MB
    _Float16* it16 = (_Float16*)(base + 59240128);      // (50000+1)*64 h = 6.4 MB
    // ends ~65.6 MB (< 67 MB known-good)

    prep_kernel<<<CVT_BLOCKS + 2, 256, 0, stream>>>(item_table, it16, ucur, w16);

    // ---- build CSR + CSC (sentinel-padded runs) ----
    pass1_kernel<<<NUM_EDGES / P1_EDGES, P1_THREADS, 0, stream>>>(
        rows, cols, ucur, icur, rec_u, rec_i);
    pass2_kernel<<<NBUCK * 2, P2_THREADS, 0, stream>>>(rec_u, ucur, udeg, updeg, uoff, inv32,
                                                       rec_i, icur, ideg, ipdeg, ioff);

    // ---- propagation ----
    const int ublocks = (NUM_USERS + 3) / 4;
    const int iblocks = (NUM_ITEMS + 3) / 4;
    for (int l = 0; l < 3; ++l) {
        gather_u<<<ublocks, 256, 0, stream>>>(uoff, updeg, rec_u, inv32, it16, w16);
        if (l < 2)
            gather_it<<<iblocks, 256, 0, stream>>>(ioff, ipdeg, rec_i, w16, it16);
    }
    batch_score<<<BATCH / 4, 256, 0, stream>>>(ioff, ipdeg, rec_i, w16, udeg,
                                               uidx, iidx, out);
}

// Round 15
// 536.531 us; speedup vs baseline: 1.0196x; 1.0196x over previous
//
#include <hip/hip_runtime.h>
#include <math.h>

#define NUM_USERS 100000
#define NUM_ITEMS 50000
#define EMBED     64
#define NUM_EDGES 3276800
#define BATCH     16384
#define CAP       13824       // fits input (~11580+5s) AND 32-padded output (~12450+12s)
#define NBUCK     391
#define P1_EDGES  8192
#define P1_THREADS 512
#define P2_THREADS 1024
#define CVT_BLOCKS 1563       // ceil(50000*64/8 / 256)

typedef _Float16 half8 __attribute__((ext_vector_type(8)));

// ---------- prep: fused cvt + workspace zeroing ----------
__global__ void prep_kernel(const float* __restrict__ itab, _Float16* __restrict__ it16,
                            int* __restrict__ curzero, _Float16* __restrict__ w16) {
    int b = blockIdx.x;
    if (b < CVT_BLOCKS) {
        int i = b * 256 + threadIdx.x;
        if (i < NUM_ITEMS * EMBED / 8) {
            const float4* p = (const float4*)itab + 2 * i;
            float4 a = p[0], c = p[1];
            half8 o;
            o[0] = (_Float16)a.x; o[1] = (_Float16)a.y; o[2] = (_Float16)a.z; o[3] = (_Float16)a.w;
            o[4] = (_Float16)c.x; o[5] = (_Float16)c.y; o[6] = (_Float16)c.z; o[7] = (_Float16)c.w;
            ((half8*)it16)[i] = o;
        }
    } else if (b == CVT_BLOCKS) {
        for (int k = threadIdx.x; k < 800; k += 256) curzero[k] = 0;
    } else {
        int i = threadIdx.x;
        if (i < 64) w16[(long long)NUM_USERS * EMBED + i] = (_Float16)0.f;
        else if (i < 128) it16[(long long)NUM_ITEMS * EMBED + (i - 64)] = (_Float16)0.f;
    }
}

// ---------- pass 1: register-stashed edges, LDS-staged line-aligned bucket scatter ----------
__global__ void __launch_bounds__(P1_THREADS)
pass1_kernel(const int* __restrict__ rows, const int* __restrict__ cols,
             int* __restrict__ ucur, int* __restrict__ icur,
             int* __restrict__ rec_u, int* __restrict__ rec_i) {
    __shared__ int hu[400], hi[400], gu[400], gi[400];
    __shared__ int lbase[400], lcur[400];
    __shared__ int sc[512];
    __shared__ int recbuf[P1_EDGES];
    int t = threadIdx.x;
    long long e0 = (long long)blockIdx.x * P1_EDGES;

    int er[16], ec[16];
    #pragma unroll
    for (int q = 0; q < 16; ++q) {
        er[q] = rows[e0 + t + q * P1_THREADS];
        ec[q] = cols[e0 + t + q * P1_THREADS];
    }

    for (int i = t; i < 400; i += P1_THREADS) { hu[i] = 0; hi[i] = 0; }
    __syncthreads();
    #pragma unroll
    for (int q = 0; q < 16; ++q) {
        atomicAdd(&hu[er[q] >> 8], 1);
        atomicAdd(&hi[ec[q] >> 7], 1);
    }
    __syncthreads();
    for (int i = t; i < 400; i += P1_THREADS) {
        int vr = (hu[i] + 15) & ~15;
        gu[i] = vr ? atomicAdd(&ucur[i], vr) : 0;
        vr = (hi[i] + 15) & ~15;
        gi[i] = vr ? atomicAdd(&icur[i], vr) : 0;
    }

    // ===== user phase =====
    __syncthreads();
    sc[t] = (t < 400) ? hu[t] : 0;
    __syncthreads();
    for (int o = 1; o < 512; o <<= 1) {
        int x = (t >= o) ? sc[t - o] : 0; __syncthreads();
        sc[t] += x; __syncthreads();
    }
    if (t < 400) { lbase[t] = sc[t] - hu[t]; lcur[t] = 0; }
    __syncthreads();
    #pragma unroll
    for (int q = 0; q < 16; ++q) {
        int b = er[q] >> 8;
        int p = lbase[b] + atomicAdd(&lcur[b], 1);
        recbuf[p] = (ec[q] << 8) | (er[q] & 255);
    }
    __syncthreads();
    sc[t] = (t < 400) ? ((hu[t] + 15) & ~15) : 0;
    __syncthreads();
    for (int o = 1; o < 512; o <<= 1) {
        int x = (t >= o) ? sc[t - o] : 0; __syncthreads();
        sc[t] += x; __syncthreads();
    }
    int total = sc[511];
    for (int o4 = t * 4; o4 < total; o4 += P1_THREADS * 4) {
        int lo = 0, hi_ = 399;
        while (lo < hi_) { int mid = (lo + hi_) >> 1; if (sc[mid] > o4) hi_ = mid; else lo = mid + 1; }
        int b = lo;
        int v = hu[b];
        int vr = (v + 15) & ~15;
        int j = o4 - (sc[b] - vr);
        int gpos = gu[b] + j;
        if (gpos + 3 < CAP) {
            int4 val;
            val.x = (j + 0 < v) ? recbuf[lbase[b] + j + 0] : -1;
            val.y = (j + 1 < v) ? recbuf[lbase[b] + j + 1] : -1;
            val.z = (j + 2 < v) ? recbuf[lbase[b] + j + 2] : -1;
            val.w = (j + 3 < v) ? recbuf[lbase[b] + j + 3] : -1;
            *(int4*)(rec_u + (long long)b * CAP + gpos) = val;
        } else {
            for (int k = 0; k < 4; ++k)
                if (gpos + k < CAP)
                    rec_u[(long long)b * CAP + gpos + k] = (j + k < v) ? recbuf[lbase[b] + j + k] : -1;
        }
    }

    // ===== item phase =====
    __syncthreads();
    sc[t] = (t < 400) ? hi[t] : 0;
    __syncthreads();
    for (int o = 1; o < 512; o <<= 1) {
        int x = (t >= o) ? sc[t - o] : 0; __syncthreads();
        sc[t] += x; __syncthreads();
    }
    if (t < 400) { lbase[t] = sc[t] - hi[t]; lcur[t] = 0; }
    __syncthreads();
    #pragma unroll
    for (int q = 0; q < 16; ++q) {
        int b = ec[q] >> 7;
        int p = lbase[b] + atomicAdd(&lcur[b], 1);
        recbuf[p] = (er[q] << 7) | (ec[q] & 127);
    }
    __syncthreads();
    sc[t] = (t < 400) ? ((hi[t] + 15) & ~15) : 0;
    __syncthreads();
    for (int o = 1; o < 512; o <<= 1) {
        int x = (t >= o) ? sc[t - o] : 0; __syncthreads();
        sc[t] += x; __syncthreads();
    }
    total = sc[511];
    for (int o4 = t * 4; o4 < total; o4 += P1_THREADS * 4) {
        int lo = 0, hi_ = 399;
        while (lo < hi_) { int mid = (lo + hi_) >> 1; if (sc[mid] > o4) hi_ = mid; else lo = mid + 1; }
        int b = lo;
        int v = hi[b];
        int vr = (v + 15) & ~15;
        int j = o4 - (sc[b] - vr);
        int gpos = gi[b] + j;
        if (gpos + 3 < CAP) {
            int4 val;
            val.x = (j + 0 < v) ? recbuf[lbase[b] + j + 0] : -1;
            val.y = (j + 1 < v) ? recbuf[lbase[b] + j + 1] : -1;
            val.z = (j + 2 < v) ? recbuf[lbase[b] + j + 2] : -1;
            val.w = (j + 3 < v) ? recbuf[lbase[b] + j + 3] : -1;
            *(int4*)(rec_i + (long long)b * CAP + gpos) = val;
        } else {
            for (int k = 0; k < 4; ++k)
                if (gpos + k < CAP)
                    rec_i[(long long)b * CAP + gpos + k] = (j + k < v) ? recbuf[lbase[b] + j + k] : -1;
        }
    }
}

// ---------- pass 2: per-bucket fine sort; runs padded to x32 with zero-row sentinel ----------
template <int VBITS>
__device__ __forceinline__ void pass2_body(int* __restrict__ rec, const int* __restrict__ cur,
                                           int* __restrict__ rdeg, int* __restrict__ pdeg,
                                           int* __restrict__ off, float* __restrict__ inv32,
                                           int ncap, int sentinel, int b,
                                           int* buf, int* h, int* ex, int* cnt, int* sc) {
    const int V = 1 << VBITS, M = V - 1;
    int t = threadIdx.x;
    long long s = (long long)b * CAP;
    int n = cur[b]; if (n > CAP) n = CAP;
    int nv = (n + 3) >> 2;
    const int4* rec4 = (const int4*)(rec + s);
    for (int i = t; i < nv; i += P2_THREADS) {
        int4 v4 = rec4[i];
        buf[4 * i + 0] = v4.x; buf[4 * i + 1] = v4.y;
        buf[4 * i + 2] = v4.z; buf[4 * i + 3] = v4.w;
    }
    if (t < V) { h[t] = 0; cnt[t] = 0; }
    __syncthreads();
    for (int i = t; i < n; i += P2_THREADS) {
        int r = buf[i];
        if (r != -1) atomicAdd(&h[r & M], 1);
    }
    __syncthreads();
    if (t < V) sc[t] = (h[t] + 31) & ~31;         // padded run length
    __syncthreads();
    for (int o = 1; o < V; o <<= 1) {
        int x = (t >= o && t < V) ? sc[t - o] : 0;
        __syncthreads();
        if (t < V) sc[t] += x;
        __syncthreads();
    }
    if (t < V) {
        int hpv = (h[t] + 31) & ~31;
        ex[t] = sc[t] - hpv;                      // exclusive padded offset
        int id = b * V + t;
        if (id < ncap) {
            int v = h[t];
            rdeg[id] = v;
            pdeg[id] = hpv;
            off[id] = (int)(s + ex[t]);
            if (inv32) inv32[id] = v ? 1.0f / (float)v : 0.0f;
        }
    }
    __syncthreads();
    for (int i = t; i < n; i += P2_THREADS) {
        int r = buf[i];
        if (r == -1) continue;
        int k = r & M;
        int rnk = atomicAdd(&cnt[k], 1);
        rec[s + ex[k] + rnk] = (int)(((unsigned)r) >> VBITS);
    }
    __syncthreads();
    if (t < V) {                                  // sentinel-fill the per-run pad
        int basep = (int)(s + ex[t]);
        int v = h[t];
        int hpv = (v + 31) & ~31;
        for (int j = v; j < hpv; ++j) rec[basep + j] = sentinel;
    }
}

__global__ void __launch_bounds__(P2_THREADS)
pass2_kernel(int* __restrict__ rec_u, const int* __restrict__ ucur,
             int* __restrict__ udeg, int* __restrict__ updeg,
             int* __restrict__ uoff, float* __restrict__ inv32,
             int* __restrict__ rec_i, const int* __restrict__ icur,
             int* __restrict__ ideg, int* __restrict__ ipdeg, int* __restrict__ ioff) {
    __shared__ int buf[CAP];
    __shared__ int h[256], ex[256], cnt[256], sc[256];
    if (blockIdx.x < NBUCK)
        pass2_body<8>(rec_u, ucur, udeg, updeg, uoff, inv32, NUM_USERS, NUM_ITEMS,
                      blockIdx.x, buf, h, ex, cnt, sc);
    else
        pass2_body<7>(rec_i, icur, ideg, ipdeg, ioff, (float*)nullptr, NUM_ITEMS, NUM_USERS,
                      blockIdx.x - NBUCK, buf, h, ex, cnt, sc);
}

// ---------- depth-8 sentinel gather core: 2x32-block main loop + wave-uniform tail ----------
__device__ __forceinline__ half8 gather_sum(const int* __restrict__ idxArr,
                                            const _Float16* __restrict__ tab,
                                            int start, int pend, int slot, int h) {
    half8 acc = {0, 0, 0, 0, 0, 0, 0, 0};
    int k = start;
    for (; k + 32 < pend; k += 64) {          // two 32-blocks: 8 loads in flight
        int c[8];
        #pragma unroll
        for (int q = 0; q < 4; ++q) c[q] = idxArr[k + slot + q * 8];
        #pragma unroll
        for (int q = 0; q < 4; ++q) c[4 + q] = idxArr[k + 32 + slot + q * 8];
        half8 x[8];
        #pragma unroll
        for (int q = 0; q < 8; ++q)
            x[q] = *(const half8*)(tab + (long long)c[q] * EMBED + (h << 3));
        #pragma unroll
        for (int q = 0; q < 8; ++q) acc += x[q];
    }
    if (k < pend) {                           // trailing single 32-block
        int c[4];
        #pragma unroll
        for (int q = 0; q < 4; ++q) c[q] = idxArr[k + slot + q * 8];
        half8 x[4];
        #pragma unroll
        for (int q = 0; q < 4; ++q)
            x[q] = *(const half8*)(tab + (long long)c[q] * EMBED + (h << 3));
        #pragma unroll
        for (int q = 0; q < 4; ++q) acc += x[q];
    }
    return acc;
}

// ---------- gather_u: writes w = invdeg^2 * sum ----------
__global__ void gather_u(const int* __restrict__ uoff, const int* __restrict__ updeg,
                         const int* __restrict__ csr_col, const float* __restrict__ inv32,
                         const _Float16* __restrict__ it, _Float16* __restrict__ w) {
    int row = blockIdx.x * 4 + (threadIdx.x >> 6);
    if (row >= NUM_USERS) return;
    int lane = threadIdx.x & 63;
    int slot = lane >> 3;
    int h    = lane & 7;
    int start = uoff[row];
    half8 acc = gather_sum(csr_col, it, start, start + updeg[row], slot, h);
    float f[8];
    #pragma unroll
    for (int j = 0; j < 8; ++j) {
        f[j] = (float)acc[j];
        f[j] += __shfl_xor(f[j], 8, 64);
        f[j] += __shfl_xor(f[j], 16, 64);
        f[j] += __shfl_xor(f[j], 32, 64);
    }
    if (lane < 8) {
        float v = inv32[row];
        float v2 = v * v;
        half8 ow;
        #pragma unroll
        for (int j = 0; j < 8; ++j) ow[j] = (_Float16)(f[j] * v2);
        *(half8*)(w + (long long)row * EMBED + (lane << 3)) = ow;
    }
}

// ---------- gather_it: plain sum of w rows ----------
__global__ void gather_it(const int* __restrict__ ioff, const int* __restrict__ ipdeg,
                          const int* __restrict__ csc_row,
                          const _Float16* __restrict__ w, _Float16* __restrict__ it) {
    int col = blockIdx.x * 4 + (threadIdx.x >> 6);
    if (col >= NUM_ITEMS) return;
    int lane = threadIdx.x & 63;
    int slot = lane >> 3;
    int h    = lane & 7;
    int start = ioff[col];
    half8 acc = gather_sum(csc_row, w, start, start + ipdeg[col], slot, h);
    float f[8];
    #pragma unroll
    for (int j = 0; j < 8; ++j) {
        f[j] = (float)acc[j];
        f[j] += __shfl_xor(f[j], 8, 64);
        f[j] += __shfl_xor(f[j], 16, 64);
        f[j] += __shfl_xor(f[j], 32, 64);
    }
    if (lane < 8) {
        half8 o;
        #pragma unroll
        for (int j = 0; j < 8; ++j) o[j] = (_Float16)f[j];
        *(half8*)(it + (long long)col * EMBED + (lane << 3)) = o;
    }
}

// ---------- fused last layer: it3 row in registers -> dot with deg*w3 -> sigmoid ----------
__global__ void batch_score(const int* __restrict__ ioff, const int* __restrict__ ipdeg,
                            const int* __restrict__ csc_row, const _Float16* __restrict__ w,
                            const int* __restrict__ udeg,
                            const int* __restrict__ uidx, const int* __restrict__ iidx,
                            float* __restrict__ out) {
    int b = blockIdx.x * 4 + (threadIdx.x >> 6);
    if (b >= BATCH) return;
    int lane = threadIdx.x & 63;
    int col = iidx[b];
    int slot = lane >> 3;
    int h    = lane & 7;
    int start = ioff[col];
    half8 acc = gather_sum(csc_row, w, start, start + ipdeg[col], slot, h);
    float f[8];
    #pragma unroll
    for (int j = 0; j < 8; ++j) {
        f[j] = (float)acc[j];
        f[j] += __shfl_xor(f[j], 8, 64);
        f[j] += __shfl_xor(f[j], 16, 64);
        f[j] += __shfl_xor(f[j], 32, 64);
    }
    int ui = uidx[b];
    half8 wv = *(const half8*)(w + (long long)ui * EMBED + (h << 3));
    float p = 0.f;
    #pragma unroll
    for (int j = 0; j < 8; ++j) p += f[j] * (float)wv[j];
    p += __shfl_xor(p, 1, 64);
    p += __shfl_xor(p, 2, 64);
    p += __shfl_xor(p, 4, 64);
    if (lane == 0) {
        float s = p * (float)udeg[ui];   // u3 = deg * w3
        out[b] = 1.0f / (1.0f + expf(-s));
    }
}

extern "C" void kernel_launch(void* const* d_in, const int* in_sizes, int n_in,
                              void* d_out, int out_size, void* d_ws, size_t ws_size,
                              hipStream_t stream) {
    const float* item_table = (const float*)d_in[1];
    const int*   rows       = (const int*)d_in[2];
    const int*   cols       = (const int*)d_in[3];
    const int*   uidx       = (const int*)d_in[4];
    const int*   iidx       = (const int*)d_in[5];
    float* out = (float*)d_out;

    // workspace layout (byte offsets)
    char* base = (char*)d_ws;
    int*   udeg  = (int*)(base + 0);                    // 100000 i (real deg)
    int*   ideg  = (int*)(base +   400000);             // 50000 i (real deg, unused downstream)
    int*   uoff  = (int*)(base +   600000);             // 100000 i
    int*   ioff  = (int*)(base +  1000000);             // 50000 i
    float* inv32 = (float*)(base + 1200000);            // 100000 f
    int*   updeg = (int*)(base +  1600000);             // 100000 i (padded deg)
    int*   ipdeg = (int*)(base +  2000000);             // 50000 i (padded deg)
    int*   ucur  = (int*)(base +  2200000);             // 400 i
    int*   icur  = (int*)(base +  2201600);             // 400 i (contiguous with ucur)
    int*   rec_u = (int*)(base +  2203200);             // 400*CAP i = 22.1 MB
    int*   rec_i = (int*)(base + 24321600);             // 400*CAP i = 22.1 MB
    _Float16* w16  = (_Float16*)(base + 46440000);      // (100000+1)*64 h = 12.8 MB
    _Float16* it16 = (_Float16*)(base + 59240128);      // (50000+1)*64 h = 6.4 MB
    // ends ~65.6 MB

    prep_kernel<<<CVT_BLOCKS + 2, 256, 0, stream>>>(item_table, it16, ucur, w16);

    // ---- build CSR + CSC (sentinel-padded runs) ----
    pass1_kernel<<<NUM_EDGES / P1_EDGES, P1_THREADS, 0, stream>>>(
        rows, cols, ucur, icur, rec_u, rec_i);
    pass2_kernel<<<NBUCK * 2, P2_THREADS, 0, stream>>>(rec_u, ucur, udeg, updeg, uoff, inv32,
                                                       rec_i, icur, ideg, ipdeg, ioff);

    // ---- propagation ----
    const int ublocks = (NUM_USERS + 3) / 4;
    const int iblocks = (NUM_ITEMS + 3) / 4;
    for (int l = 0; l < 3; ++l) {
        gather_u<<<ublocks, 256, 0, stream>>>(uoff, updeg, rec_u, inv32, it16, w16);
        if (l < 2)
            gather_it<<<iblocks, 256, 0, stream>>>(ioff, ipdeg, rec_i, w16, it16);
    }
    batch_score<<<BATCH / 4, 256, 0, stream>>>(ioff, ipdeg, rec_i, w16, udeg,
                                               uidx, iidx, out);
}

// Round 16
// 411.949 us; speedup vs baseline: 1.3279x; 1.3024x over previous
//
#include <hip/hip_runtime.h>
#include <math.h>

#define NUM_USERS 100000
#define NUM_ITEMS 50000
#define EMBED     64
#define NUM_EDGES 3276800
#define BATCH     16384
#define CAP       12800       // padded mean ~11380 + ~11 sigma (400 p1 blocks)
#define NBUCK     391
#define P1_EDGES  8192
#define P1_THREADS 512
#define P2_THREADS 1024
#define CVT_GROUPS (NUM_ITEMS * 8)                  // 400000 half8 groups
#define CVT_BLOCKS ((CVT_GROUPS + P1_THREADS - 1) / P1_THREADS)  // 782

typedef _Float16 half8 __attribute__((ext_vector_type(8)));

// ---------- fused build: pass1 (blocks 0..399) + cvt (400..1181) + zero rows (1182) ----------
__global__ void __launch_bounds__(P1_THREADS)
build_kernel(const int* __restrict__ rows, const int* __restrict__ cols,
             const float* __restrict__ itab, _Float16* __restrict__ it16,
             _Float16* __restrict__ w16,
             int* __restrict__ ucur, int* __restrict__ icur,
             int* __restrict__ rec_u, int* __restrict__ rec_i) {
    __shared__ int hu[400], hi[400], gu[400], gi[400];
    __shared__ int lbase[400], lcur[400];
    __shared__ int sc[512];
    __shared__ int recbuf[P1_EDGES];
    int t = threadIdx.x;

    if (blockIdx.x >= 400) {
        int b = blockIdx.x - 400;
        if (b < CVT_BLOCKS) {
            int i = b * P1_THREADS + t;
            if (i < CVT_GROUPS) {
                const float4* p = (const float4*)itab + 2 * i;
                float4 a = p[0], c = p[1];
                half8 o;
                o[0] = (_Float16)a.x; o[1] = (_Float16)a.y; o[2] = (_Float16)a.z; o[3] = (_Float16)a.w;
                o[4] = (_Float16)c.x; o[5] = (_Float16)c.y; o[6] = (_Float16)c.z; o[7] = (_Float16)c.w;
                ((half8*)it16)[i] = o;
            }
        } else {
            if (t < 64) w16[(long long)NUM_USERS * EMBED + t] = (_Float16)0.f;
            else if (t < 128) it16[(long long)NUM_ITEMS * EMBED + (t - 64)] = (_Float16)0.f;
        }
        return;
    }

    long long e0 = (long long)blockIdx.x * P1_EDGES;
    int er[16], ec[16];
    #pragma unroll
    for (int q = 0; q < 16; ++q) {
        er[q] = rows[e0 + t + q * P1_THREADS];
        ec[q] = cols[e0 + t + q * P1_THREADS];
    }

    for (int i = t; i < 400; i += P1_THREADS) { hu[i] = 0; hi[i] = 0; }
    __syncthreads();
    #pragma unroll
    for (int q = 0; q < 16; ++q) {
        atomicAdd(&hu[er[q] >> 8], 1);
        atomicAdd(&hi[ec[q] >> 7], 1);
    }
    __syncthreads();
    for (int i = t; i < 400; i += P1_THREADS) {
        int vr = (hu[i] + 15) & ~15;
        gu[i] = vr ? atomicAdd(&ucur[i], vr) : 0;
        vr = (hi[i] + 15) & ~15;
        gi[i] = vr ? atomicAdd(&icur[i], vr) : 0;
    }

    // ===== user phase =====
    __syncthreads();
    sc[t] = (t < 400) ? hu[t] : 0;
    __syncthreads();
    for (int o = 1; o < 512; o <<= 1) {
        int x = (t >= o) ? sc[t - o] : 0; __syncthreads();
        sc[t] += x; __syncthreads();
    }
    if (t < 400) { lbase[t] = sc[t] - hu[t]; lcur[t] = 0; }
    __syncthreads();
    #pragma unroll
    for (int q = 0; q < 16; ++q) {
        int b = er[q] >> 8;
        int p = lbase[b] + atomicAdd(&lcur[b], 1);
        recbuf[p] = (ec[q] << 8) | (er[q] & 255);
    }
    __syncthreads();
    sc[t] = (t < 400) ? ((hu[t] + 15) & ~15) : 0;
    __syncthreads();
    for (int o = 1; o < 512; o <<= 1) {
        int x = (t >= o) ? sc[t - o] : 0; __syncthreads();
        sc[t] += x; __syncthreads();
    }
    int total = sc[511];
    for (int o4 = t * 4; o4 < total; o4 += P1_THREADS * 4) {
        int lo = 0, hi_ = 399;
        while (lo < hi_) { int mid = (lo + hi_) >> 1; if (sc[mid] > o4) hi_ = mid; else lo = mid + 1; }
        int b = lo;
        int v = hu[b];
        int vr = (v + 15) & ~15;
        int j = o4 - (sc[b] - vr);
        int gpos = gu[b] + j;
        if (gpos + 3 < CAP) {
            int4 val;
            val.x = (j + 0 < v) ? recbuf[lbase[b] + j + 0] : -1;
            val.y = (j + 1 < v) ? recbuf[lbase[b] + j + 1] : -1;
            val.z = (j + 2 < v) ? recbuf[lbase[b] + j + 2] : -1;
            val.w = (j + 3 < v) ? recbuf[lbase[b] + j + 3] : -1;
            *(int4*)(rec_u + (long long)b * CAP + gpos) = val;
        } else {
            for (int k = 0; k < 4; ++k)
                if (gpos + k < CAP)
                    rec_u[(long long)b * CAP + gpos + k] = (j + k < v) ? recbuf[lbase[b] + j + k] : -1;
        }
    }

    // ===== item phase =====
    __syncthreads();
    sc[t] = (t < 400) ? hi[t] : 0;
    __syncthreads();
    for (int o = 1; o < 512; o <<= 1) {
        int x = (t >= o) ? sc[t - o] : 0; __syncthreads();
        sc[t] += x; __syncthreads();
    }
    if (t < 400) { lbase[t] = sc[t] - hi[t]; lcur[t] = 0; }
    __syncthreads();
    #pragma unroll
    for (int q = 0; q < 16; ++q) {
        int b = ec[q] >> 7;
        int p = lbase[b] + atomicAdd(&lcur[b], 1);
        recbuf[p] = (er[q] << 7) | (ec[q] & 127);
    }
    __syncthreads();
    sc[t] = (t < 400) ? ((hi[t] + 15) & ~15) : 0;
    __syncthreads();
    for (int o = 1; o < 512; o <<= 1) {
        int x = (t >= o) ? sc[t - o] : 0; __syncthreads();
        sc[t] += x; __syncthreads();
    }
    total = sc[511];
    for (int o4 = t * 4; o4 < total; o4 += P1_THREADS * 4) {
        int lo = 0, hi_ = 399;
        while (lo < hi_) { int mid = (lo + hi_) >> 1; if (sc[mid] > o4) hi_ = mid; else lo = mid + 1; }
        int b = lo;
        int v = hi[b];
        int vr = (v + 15) & ~15;
        int j = o4 - (sc[b] - vr);
        int gpos = gi[b] + j;
        if (gpos + 3 < CAP) {
            int4 val;
            val.x = (j + 0 < v) ? recbuf[lbase[b] + j + 0] : -1;
            val.y = (j + 1 < v) ? recbuf[lbase[b] + j + 1] : -1;
            val.z = (j + 2 < v) ? recbuf[lbase[b] + j + 2] : -1;
            val.w = (j + 3 < v) ? recbuf[lbase[b] + j + 3] : -1;
            *(int4*)(rec_i + (long long)b * CAP + gpos) = val;
        } else {
            for (int k = 0; k < 4; ++k)
                if (gpos + k < CAP)
                    rec_i[(long long)b * CAP + gpos + k] = (j + k < v) ? recbuf[lbase[b] + j + k] : -1;
        }
    }
}

// ---------- pass 2: per-bucket fine sort in LDS, 1024 threads, int4 slab load ----------
template <int VBITS>
__device__ __forceinline__ void pass2_body(int* __restrict__ rec, const int* __restrict__ cur,
                                           int* __restrict__ deg, int* __restrict__ off,
                                           float* __restrict__ inv32, int ncap, int b,
                                           int* buf, int* h, int* ex, int* cnt, int* sc) {
    const int V = 1 << VBITS, M = V - 1;
    int t = threadIdx.x;
    long long s = (long long)b * CAP;
    int n = cur[b]; if (n > CAP) n = CAP;
    int nv = (n + 3) >> 2;
    const int4* rec4 = (const int4*)(rec + s);
    for (int i = t; i < nv; i += P2_THREADS) {
        int4 v4 = rec4[i];
        buf[4 * i + 0] = v4.x; buf[4 * i + 1] = v4.y;
        buf[4 * i + 2] = v4.z; buf[4 * i + 3] = v4.w;
    }
    if (t < V) { h[t] = 0; cnt[t] = 0; }
    __syncthreads();
    for (int i = t; i < n; i += P2_THREADS) {
        int r = buf[i];
        if (r != -1) atomicAdd(&h[r & M], 1);
    }
    __syncthreads();
    if (t < V) sc[t] = h[t];
    __syncthreads();
    for (int o = 1; o < V; o <<= 1) {
        int x = (t >= o && t < V) ? sc[t - o] : 0;
        __syncthreads();
        if (t < V) sc[t] += x;
        __syncthreads();
    }
    if (t < V) {
        ex[t] = sc[t] - h[t];
        int id = b * V + t;
        if (id < ncap) {
            int v = h[t];
            deg[id] = v;
            off[id] = (int)(s + ex[t]);
            if (inv32) inv32[id] = v ? 1.0f / (float)v : 0.0f;
        }
    }
    __syncthreads();
    for (int i = t; i < n; i += P2_THREADS) {
        int r = buf[i];
        if (r == -1) continue;
        int k = r & M;
        int rnk = atomicAdd(&cnt[k], 1);
        rec[s + ex[k] + rnk] = (int)(((unsigned)r) >> VBITS);
    }
}

__global__ void __launch_bounds__(P2_THREADS)
pass2_kernel(int* __restrict__ rec_u, const int* __restrict__ ucur,
             int* __restrict__ udeg, int* __restrict__ uoff, float* __restrict__ inv32,
             int* __restrict__ rec_i, const int* __restrict__ icur,
             int* __restrict__ ideg, int* __restrict__ ioff) {
    __shared__ int buf[CAP];
    __shared__ int h[256], ex[256], cnt[256], sc[256];
    if (blockIdx.x < NBUCK)
        pass2_body<8>(rec_u, ucur, udeg, uoff, inv32, NUM_USERS, blockIdx.x,
                      buf, h, ex, cnt, sc);
    else
        pass2_body<7>(rec_i, icur, ideg, ioff, (float*)nullptr, NUM_ITEMS,
                      blockIdx.x - NBUCK, buf, h, ex, cnt, sc);
}

// ---------- gather SpMM (u): 8-deep clamped uniform loop (R13 — do not restructure) ----------
__global__ void gather_u(const int* __restrict__ uoff, const int* __restrict__ udeg,
                         const int* __restrict__ csr_col, const float* __restrict__ inv32,
                         const _Float16* __restrict__ it, _Float16* __restrict__ w) {
    int row = blockIdx.x * 4 + (threadIdx.x >> 6);
    if (row >= NUM_USERS) return;
    int lane = threadIdx.x & 63;
    int slot = lane >> 3;
    int h    = lane & 7;
    int start = uoff[row];
    int end = start + udeg[row];
    half8 acc = {0, 0, 0, 0, 0, 0, 0, 0};
    for (int k = start; k < end; k += 64) {
        int e1 = end - 1;
        int idx[8], c[8];
        #pragma unroll
        for (int q = 0; q < 8; ++q) {
            idx[q] = k + slot + q * 8;
            int safe = idx[q] < e1 ? idx[q] : e1;
            c[q] = csr_col[safe];
            c[q] = idx[q] < end ? c[q] : NUM_ITEMS;   // zero row
        }
        half8 x[8];
        #pragma unroll
        for (int q = 0; q < 8; ++q)
            x[q] = *(const half8*)(it + (long long)c[q] * EMBED + (h << 3));
        #pragma unroll
        for (int q = 0; q < 8; ++q) acc += x[q];
    }
    float f[8];
    #pragma unroll
    for (int j = 0; j < 8; ++j) {
        f[j] = (float)acc[j];
        f[j] += __shfl_xor(f[j], 8, 64);
        f[j] += __shfl_xor(f[j], 16, 64);
        f[j] += __shfl_xor(f[j], 32, 64);
    }
    if (lane < 8) {
        float v = inv32[row];
        float v2 = v * v;
        half8 ow;
        #pragma unroll
        for (int j = 0; j < 8; ++j) ow[j] = (_Float16)(f[j] * v2);
        *(half8*)(w + (long long)row * EMBED + (lane << 3)) = ow;
    }
}

// ---------- gather SpMM (it): 8-deep clamped uniform loop ----------
__global__ void gather_it(const int* __restrict__ ioff, const int* __restrict__ ideg,
                          const int* __restrict__ csc_row,
                          const _Float16* __restrict__ w, _Float16* __restrict__ it) {
    int col = blockIdx.x * 4 + (threadIdx.x >> 6);
    if (col >= NUM_ITEMS) return;
    int lane = threadIdx.x & 63;
    int slot = lane >> 3;
    int h    = lane & 7;
    int start = ioff[col];
    int end = start + ideg[col];
    half8 acc = {0, 0, 0, 0, 0, 0, 0, 0};
    for (int k = start; k < end; k += 64) {
        int e1 = end - 1;
        int idx[8], r[8];
        #pragma unroll
        for (int q = 0; q < 8; ++q) {
            idx[q] = k + slot + q * 8;
            int safe = idx[q] < e1 ? idx[q] : e1;
            r[q] = csc_row[safe];
            r[q] = idx[q] < end ? r[q] : NUM_USERS;   // zero row
        }
        half8 x[8];
        #pragma unroll
        for (int q = 0; q < 8; ++q)
            x[q] = *(const half8*)(w + (long long)r[q] * EMBED + (h << 3));
        #pragma unroll
        for (int q = 0; q < 8; ++q) acc += x[q];
    }
    float f[8];
    #pragma unroll
    for (int j = 0; j < 8; ++j) {
        f[j] = (float)acc[j];
        f[j] += __shfl_xor(f[j], 8, 64);
        f[j] += __shfl_xor(f[j], 16, 64);
        f[j] += __shfl_xor(f[j], 32, 64);
    }
    if (lane < 8) {
        half8 o;
        #pragma unroll
        for (int j = 0; j < 8; ++j) o[j] = (_Float16)f[j];
        *(half8*)(it + (long long)col * EMBED + (lane << 3)) = o;
    }
}

// ---------- fused last layer: it3 row in registers -> dot with deg*w3 -> sigmoid ----------
__global__ void batch_score(const int* __restrict__ ioff, const int* __restrict__ ideg,
                            const int* __restrict__ csc_row, const _Float16* __restrict__ w,
                            const int* __restrict__ udeg,
                            const int* __restrict__ uidx, const int* __restrict__ iidx,
                            float* __restrict__ out) {
    int b = blockIdx.x * 4 + (threadIdx.x >> 6);
    if (b >= BATCH) return;
    int lane = threadIdx.x & 63;
    int col = iidx[b];
    int slot = lane >> 3;
    int h    = lane & 7;
    int start = ioff[col];
    int end = start + ideg[col];
    half8 acc = {0, 0, 0, 0, 0, 0, 0, 0};
    for (int k = start; k < end; k += 64) {
        int e1 = end - 1;
        int idx[8], r[8];
        #pragma unroll
        for (int q = 0; q < 8; ++q) {
            idx[q] = k + slot + q * 8;
            int safe = idx[q] < e1 ? idx[q] : e1;
            r[q] = csc_row[safe];
            r[q] = idx[q] < end ? r[q] : NUM_USERS;
        }
        half8 x[8];
        #pragma unroll
        for (int q = 0; q < 8; ++q)
            x[q] = *(const half8*)(w + (long long)r[q] * EMBED + (h << 3));
        #pragma unroll
        for (int q = 0; q < 8; ++q) acc += x[q];
    }
    float f[8];
    #pragma unroll
    for (int j = 0; j < 8; ++j) {
        f[j] = (float)acc[j];
        f[j] += __shfl_xor(f[j], 8, 64);
        f[j] += __shfl_xor(f[j], 16, 64);
        f[j] += __shfl_xor(f[j], 32, 64);
    }
    int ui = uidx[b];
    half8 wv = *(const half8*)(w + (long long)ui * EMBED + (h << 3));
    float p = 0.f;
    #pragma unroll
    for (int j = 0; j < 8; ++j) p += f[j] * (float)wv[j];
    p += __shfl_xor(p, 1, 64);
    p += __shfl_xor(p, 2, 64);
    p += __shfl_xor(p, 4, 64);
    if (lane == 0) {
        float s = p * (float)udeg[ui];   // u3 = deg * w3
        out[b] = 1.0f / (1.0f + expf(-s));
    }
}

extern "C" void kernel_launch(void* const* d_in, const int* in_sizes, int n_in,
                              void* d_out, int out_size, void* d_ws, size_t ws_size,
                              hipStream_t stream) {
    const float* item_table = (const float*)d_in[1];
    const int*   rows       = (const int*)d_in[2];
    const int*   cols       = (const int*)d_in[3];
    const int*   uidx       = (const int*)d_in[4];
    const int*   iidx       = (const int*)d_in[5];
    float* out = (float*)d_out;

    // workspace layout (byte offsets) — R13 layout
    char* base = (char*)d_ws;
    int*   udeg  = (int*)(base + 0);                    // 100000 i
    int*   ideg  = (int*)(base +   400000);             // 50000 i
    int*   uoff  = (int*)(base +   600000);             // 100000 i
    int*   ioff  = (int*)(base +  1000000);             // 50000 i
    float* inv32 = (float*)(base + 1200000);            // 100000 f
    int*   ucur  = (int*)(base +  1600000);             // 400 i
    int*   icur  = (int*)(base +  1601600);             // 400 i (contiguous)
    int*   rec_u = (int*)(base +  1720320);             // 400*CAP i = 20.48 MB
    int*   rec_i = (int*)(base + 22200320);             // 400*CAP i = 20.48 MB
    _Float16* w16  = (_Float16*)(base + 42680320);      // (100000+1)*64 h
    _Float16* it16 = (_Float16*)(base + 55480448);      // (50000+1)*64 h
    // ends ~61.9 MB

    // cursors must be zero BEFORE build_kernel (same-dispatch ordering is undefined)
    (void)hipMemsetAsync(ucur, 0, 3200, stream);

    // ---- fused build: pass1 + cvt + zero-rows in one dispatch ----
    build_kernel<<<400 + CVT_BLOCKS + 1, P1_THREADS, 0, stream>>>(
        rows, cols, item_table, it16, w16, ucur, icur, rec_u, rec_i);
    pass2_kernel<<<NBUCK * 2, P2_THREADS, 0, stream>>>(rec_u, ucur, udeg, uoff, inv32,
                                                       rec_i, icur, ideg, ioff);

    // ---- propagation ----
    const int ublocks = (NUM_USERS + 3) / 4;
    const int iblocks = (NUM_ITEMS + 3) / 4;
    for (int l = 0; l < 3; ++l) {
        gather_u<<<ublocks, 256, 0, stream>>>(uoff, udeg, rec_u, inv32, it16, w16);
        if (l < 2)
            gather_it<<<iblocks, 256, 0, stream>>>(ioff, ideg, rec_i, w16, it16);
    }
    batch_score<<<BATCH / 4, 256, 0, stream>>>(ioff, ideg, rec_i, w16, udeg,
                                               uidx, iidx, out);
}